// Round 7
// baseline (407.151 us; speedup 1.0000x reference)
//
#include <hip/hip_runtime.h>

#define NS 32768
#define NC 395
#define FD 512
#define SPL 8
#define CHUNK (NS / SPL)   // 4096 targets scanned per block
#define TPB 256
#define GRID (NC * SPL)    // 3160 blocks
#define RED 256            // reducer blocks (must be < resident capacity)
#define NEL (NC * FD)      // 202240
#define PER (NEL / RED)    // 790 elements per reducer block

// Static device scratch — every slot rewritten each call.
__device__ float g_partial[SPL * 2 * NC * FD];  // ~13 MB
__device__ int   g_pcount[SPL * NC];

// ---------------------------------------------------------------------------
__device__ __forceinline__ void f4add(float4& a, const float4 b) {
    a.x += b.x; a.y += b.y; a.z += b.z; a.w += b.w;
}
__device__ __forceinline__ float smooth_l1(float d) {
    d = fabsf(d);
    return d < 1.0f ? 0.5f * d * d : d - 0.5f;
}

// One block per (class, split): scan 4096 targets via 4 hoisted int4 loads,
// compact matches to LDS, gather rows with register accumulation (8-deep
// unroll), write private partial slab. Then: release-increment done counter;
// blocks 0..255 acquire-spin until all GRID blocks published, and compute the
// final SmoothL1 reduction over warm partials (790 elements each).
__global__ __launch_bounds__(TPB)
void fused_kernel(const float4* __restrict__ m1,
                  const float4* __restrict__ m2,
                  const int* __restrict__ targets,
                  const float* __restrict__ centers,
                  float* __restrict__ out,
                  int* __restrict__ done) {
    int c   = blockIdx.x >> 3;        // class
    int s   = blockIdx.x & (SPL - 1); // split
    int tid = threadIdx.x;

    __shared__ int sidx[CHUNK];   // worst case: whole chunk one class (16 KB)
    __shared__ int scnt;
    if (tid == 0) scnt = 0;
    __syncthreads();

    // ---- scan phase: 4 int4 loads/thread, one vmcnt round ----
    int sbase = s * CHUNK;
    const int4* t4 = reinterpret_cast<const int4*>(targets + sbase);
    int4 ta = t4[tid];
    int4 tb = t4[tid + TPB];
    int4 tc = t4[tid + 2 * TPB];
    int4 td = t4[tid + 3 * TPB];
    int i0 = sbase + 4 * tid;
    int i1 = sbase + 4 * (tid + TPB);
    int i2 = sbase + 4 * (tid + 2 * TPB);
    int i3 = sbase + 4 * (tid + 3 * TPB);
    if (ta.x == c) sidx[atomicAdd(&scnt, 1)] = i0;
    if (ta.y == c) sidx[atomicAdd(&scnt, 1)] = i0 + 1;
    if (ta.z == c) sidx[atomicAdd(&scnt, 1)] = i0 + 2;
    if (ta.w == c) sidx[atomicAdd(&scnt, 1)] = i0 + 3;
    if (tb.x == c) sidx[atomicAdd(&scnt, 1)] = i1;
    if (tb.y == c) sidx[atomicAdd(&scnt, 1)] = i1 + 1;
    if (tb.z == c) sidx[atomicAdd(&scnt, 1)] = i1 + 2;
    if (tb.w == c) sidx[atomicAdd(&scnt, 1)] = i1 + 3;
    if (tc.x == c) sidx[atomicAdd(&scnt, 1)] = i2;
    if (tc.y == c) sidx[atomicAdd(&scnt, 1)] = i2 + 1;
    if (tc.z == c) sidx[atomicAdd(&scnt, 1)] = i2 + 2;
    if (tc.w == c) sidx[atomicAdd(&scnt, 1)] = i2 + 3;
    if (td.x == c) sidx[atomicAdd(&scnt, 1)] = i3;
    if (td.y == c) sidx[atomicAdd(&scnt, 1)] = i3 + 1;
    if (td.z == c) sidx[atomicAdd(&scnt, 1)] = i3 + 2;
    if (td.w == c) sidx[atomicAdd(&scnt, 1)] = i3 + 3;
    __syncthreads();
    int cnt = scnt;

    // ---- gather phase: register accumulation, 8-deep unroll ----
    int m = tid >> 7;             // modality (wave-uniform)
    int q = tid & 127;            // float4 quad within the 512-dim row
    const float4* src = m ? m2 : m1;

    float4 a0 = make_float4(0.f, 0.f, 0.f, 0.f);
    float4 a1 = a0, a2 = a0, a3 = a0;

    int j = 0;
    for (; j + 8 <= cnt; j += 8) {
        float4 v0 = src[(size_t)sidx[j]     * 128 + q];
        float4 v1 = src[(size_t)sidx[j + 1] * 128 + q];
        float4 v2 = src[(size_t)sidx[j + 2] * 128 + q];
        float4 v3 = src[(size_t)sidx[j + 3] * 128 + q];
        float4 v4 = src[(size_t)sidx[j + 4] * 128 + q];
        float4 v5 = src[(size_t)sidx[j + 5] * 128 + q];
        float4 v6 = src[(size_t)sidx[j + 6] * 128 + q];
        float4 v7 = src[(size_t)sidx[j + 7] * 128 + q];
        f4add(a0, v0); f4add(a1, v1); f4add(a2, v2); f4add(a3, v3);
        f4add(a0, v4); f4add(a1, v5); f4add(a2, v6); f4add(a3, v7);
    }
    for (; j + 4 <= cnt; j += 4) {
        float4 v0 = src[(size_t)sidx[j]     * 128 + q];
        float4 v1 = src[(size_t)sidx[j + 1] * 128 + q];
        float4 v2 = src[(size_t)sidx[j + 2] * 128 + q];
        float4 v3 = src[(size_t)sidx[j + 3] * 128 + q];
        f4add(a0, v0); f4add(a1, v1); f4add(a2, v2); f4add(a3, v3);
    }
    for (; j < cnt; j++)
        f4add(a0, src[(size_t)sidx[j] * 128 + q]);
    f4add(a0, a1); f4add(a2, a3); f4add(a0, a2);

    // partial[(s*2+m)][c][q*4..] — always written (zeros if no matches).
    float4* dst = reinterpret_cast<float4*>(g_partial);
    dst[(((size_t)s * 2 + m) * NC + c) * 128 + q] = a0;
    if (tid == 0) g_pcount[s * NC + c] = cnt;

    // ---- publish: barrier drains stores to L2; release add writes back L2 ----
    __syncthreads();
    if (tid == 0)
        __hip_atomic_fetch_add(done, 1, __ATOMIC_RELEASE, __HIP_MEMORY_SCOPE_AGENT);

    // ---- reducers: wait for all publishes, then loss over warm partials ----
    if (blockIdx.x >= RED) return;

    if (tid == 0) {
        while (__hip_atomic_load(done, __ATOMIC_ACQUIRE, __HIP_MEMORY_SCOPE_AGENT) < GRID)
            __builtin_amdgcn_s_sleep(32);
    }
    __syncthreads();   // all waves ordered after the acquire

    float val = 0.0f;
    int ebase = blockIdx.x * PER;
    for (int e = tid; e < PER; e += TPB) {
        int gid = ebase + e;
        int cc = gid >> 9;  // FD == 512
        int icnt = 0;
        #pragma unroll
        for (int k = 0; k < SPL; k++) icnt += g_pcount[k * NC + cc];
        if (icnt > 0) {
            float s1 = 0.0f, s2 = 0.0f;
            #pragma unroll
            for (int k = 0; k < SPL; k++) {
                s1 += g_partial[(size_t)(2 * k)     * NEL + gid];
                s2 += g_partial[(size_t)(2 * k + 1) * NEL + gid];
            }
            float fc = (float)icnt;
            float ctr = centers[gid];
            float inv = 1.0f / fc;
            val += fc * (smooth_l1(s1 * inv - ctr) + smooth_l1(s2 * inv - ctr));
        }
    }

    for (int off = 32; off > 0; off >>= 1)
        val += __shfl_down(val, off, 64);
    __shared__ float wsum[4];
    int lane = tid & 63, wid = tid >> 6;
    if (lane == 0) wsum[wid] = val;
    __syncthreads();
    if (tid == 0) {
        float sm = wsum[0] + wsum[1] + wsum[2] + wsum[3];
        atomicAdd(out, sm * 5.9604644775390625e-08f);  // 1/(N*D) = 2^-24
    }
}

extern "C" void kernel_launch(void* const* d_in, const int* in_sizes, int n_in,
                              void* d_out, int out_size, void* d_ws, size_t ws_size,
                              hipStream_t stream) {
    const float4* m1 = (const float4*)d_in[0];
    const float4* m2 = (const float4*)d_in[1];
    const float* centers = (const float*)d_in[2];
    const int* targets = (const int*)d_in[3];
    float* out = (float*)d_out;
    int* done = (int*)d_ws;   // poisoned 0xAA each call -> memset to 0 below

    hipMemsetAsync(done, 0, sizeof(int), stream);
    hipMemsetAsync(out, 0, sizeof(float), stream);
    fused_kernel<<<GRID, TPB, 0, stream>>>(m1, m2, targets, centers, out, done);
}

// Round 8
// 167.888 us; speedup vs baseline: 2.4251x; 2.4251x over previous
//
#include <hip/hip_runtime.h>

#define NS 32768
#define NC 395
#define FD 512
#define SPL 8
#define CHUNK (NS / SPL)   // 4096 targets scanned per block
#define TPB 256
#define NEL (NC * FD)

// Static device scratch — every slot rewritten each call.
__device__ float g_partial[SPL * 2 * NC * FD];  // ~13 MB
__device__ int   g_pcount[SPL * NC];

// ---------------------------------------------------------------------------
__device__ __forceinline__ void f4add(float4& a, const float4 b) {
    a.x += b.x; a.y += b.y; a.z += b.z; a.w += b.w;
}

// K1: one block per (class, split). Scan: 4 hoisted int4 loads/thread (one
// vmcnt round), LDS compaction. Gather: 4 waves = 2 per modality; within a
// modality the two waves take even/odd rows and each LANE covers a full 2KB
// row (two float4 at lane, lane+64) -> 8 distinct rows in flight per modality
// per block (2x R6). Waves combine via LDS, store private partial slab.
__global__ __launch_bounds__(TPB)
void gather_sum_kernel(const float4* __restrict__ m1,
                       const float4* __restrict__ m2,
                       const int* __restrict__ targets,
                       float* __restrict__ out) {
    int c   = blockIdx.x >> 3;        // class
    int s   = blockIdx.x & (SPL - 1); // split
    int tid = threadIdx.x;

    if (blockIdx.x == 0 && tid == 0) out[0] = 0.0f;  // zero before loss kernel

    __shared__ int sidx[CHUNK];       // worst case: whole chunk one class (16 KB)
    __shared__ int scnt;
    __shared__ float4 cmb[2][128];    // wave-pair combine buffer (4 KB)

    // ---- scan phase: 4 int4 loads issued before the zeroing barrier ----
    int sbase = s * CHUNK;
    const int4* t4 = reinterpret_cast<const int4*>(targets + sbase);
    int4 ta = t4[tid];
    int4 tb = t4[tid + TPB];
    int4 tc = t4[tid + 2 * TPB];
    int4 td = t4[tid + 3 * TPB];
    if (tid == 0) scnt = 0;
    __syncthreads();
    int i0 = sbase + 4 * tid;
    int i1 = sbase + 4 * (tid + TPB);
    int i2 = sbase + 4 * (tid + 2 * TPB);
    int i3 = sbase + 4 * (tid + 3 * TPB);
    if (ta.x == c) sidx[atomicAdd(&scnt, 1)] = i0;
    if (ta.y == c) sidx[atomicAdd(&scnt, 1)] = i0 + 1;
    if (ta.z == c) sidx[atomicAdd(&scnt, 1)] = i0 + 2;
    if (ta.w == c) sidx[atomicAdd(&scnt, 1)] = i0 + 3;
    if (tb.x == c) sidx[atomicAdd(&scnt, 1)] = i1;
    if (tb.y == c) sidx[atomicAdd(&scnt, 1)] = i1 + 1;
    if (tb.z == c) sidx[atomicAdd(&scnt, 1)] = i1 + 2;
    if (tb.w == c) sidx[atomicAdd(&scnt, 1)] = i1 + 3;
    if (tc.x == c) sidx[atomicAdd(&scnt, 1)] = i2;
    if (tc.y == c) sidx[atomicAdd(&scnt, 1)] = i2 + 1;
    if (tc.z == c) sidx[atomicAdd(&scnt, 1)] = i2 + 2;
    if (tc.w == c) sidx[atomicAdd(&scnt, 1)] = i2 + 3;
    if (td.x == c) sidx[atomicAdd(&scnt, 1)] = i3;
    if (td.y == c) sidx[atomicAdd(&scnt, 1)] = i3 + 1;
    if (td.z == c) sidx[atomicAdd(&scnt, 1)] = i3 + 2;
    if (td.w == c) sidx[atomicAdd(&scnt, 1)] = i3 + 3;
    __syncthreads();
    int cnt = scnt;

    // ---- gather phase ----
    int wid  = tid >> 6;      // wave 0..3
    int mod  = wid >> 1;      // modality (wave-uniform)
    int wsub = wid & 1;       // even/odd row subset (wave-uniform)
    int lane = tid & 63;
    const float4* src = mod ? m2 : m1;

    float4 z = make_float4(0.f, 0.f, 0.f, 0.f);
    float4 aA0 = z, aB0 = z, aA1 = z, aB1 = z;

    int j = wsub;
    // 4 rows per iteration (strided 2 within this wave), 8 loads in flight.
    for (; j + 6 < cnt; j += 8) {
        const float4* p0 = src + (size_t)sidx[j]     * 128;
        const float4* p1 = src + (size_t)sidx[j + 2] * 128;
        const float4* p2 = src + (size_t)sidx[j + 4] * 128;
        const float4* p3 = src + (size_t)sidx[j + 6] * 128;
        float4 vA0 = p0[lane], vB0 = p0[lane + 64];
        float4 vA1 = p1[lane], vB1 = p1[lane + 64];
        float4 vA2 = p2[lane], vB2 = p2[lane + 64];
        float4 vA3 = p3[lane], vB3 = p3[lane + 64];
        f4add(aA0, vA0); f4add(aB0, vB0);
        f4add(aA1, vA1); f4add(aB1, vB1);
        f4add(aA0, vA2); f4add(aB0, vB2);
        f4add(aA1, vA3); f4add(aB1, vB3);
    }
    for (; j < cnt; j += 2) {
        const float4* p = src + (size_t)sidx[j] * 128;
        f4add(aA0, p[lane]); f4add(aB0, p[lane + 64]);
    }
    f4add(aA0, aA1); f4add(aB0, aB1);

    // ---- combine the wave pair, store partial slab ----
    if (wsub == 0) {
        cmb[mod][lane]      = aA0;
        cmb[mod][lane + 64] = aB0;
    }
    __syncthreads();
    if (wsub == 1) {
        float4 rA = cmb[mod][lane];      f4add(rA, aA0);
        float4 rB = cmb[mod][lane + 64]; f4add(rB, aB0);
        float4* dst = reinterpret_cast<float4*>(g_partial);
        size_t base = (((size_t)s * 2 + mod) * NC + c) * 128;
        dst[base + lane]      = rA;
        dst[base + lane + 64] = rB;
    }
    if (tid == 0) g_pcount[s * NC + c] = cnt;
}

// ---------------------------------------------------------------------------
__device__ __forceinline__ float smooth_l1(float d) {
    d = fabsf(d);
    return d < 1.0f ? 0.5f * d * d : d - 0.5f;
}

// K2: combine partials + counts, SmoothL1 weighted by count, two-level reduce.
__global__ void loss_kernel(const float* __restrict__ centers,
                            float* __restrict__ out) {
    __shared__ float scnt[NC];
    int t = threadIdx.x;   // 256
    for (int c = t; c < NC; c += 256) {
        int sc = 0;
        #pragma unroll
        for (int k = 0; k < SPL; k++) sc += g_pcount[k * NC + c];
        scnt[c] = (float)sc;
    }
    __syncthreads();

    float val = 0.0f;
    for (int gid = blockIdx.x * 256 + t; gid < NEL; gid += gridDim.x * 256) {
        int c = gid >> 9;          // FD == 512
        float cnt = scnt[c];
        if (cnt > 0.0f) {
            float s1 = 0.0f, s2 = 0.0f;
            #pragma unroll
            for (int k = 0; k < SPL; k++) {
                s1 += g_partial[(size_t)(2 * k)     * NEL + gid];
                s2 += g_partial[(size_t)(2 * k + 1) * NEL + gid];
            }
            float ctr = centers[gid];
            float inv = 1.0f / cnt;
            val += cnt * (smooth_l1(s1 * inv - ctr) + smooth_l1(s2 * inv - ctr));
        }
    }

    for (int off = 32; off > 0; off >>= 1)
        val += __shfl_down(val, off, 64);
    __shared__ float wsum[4];
    int lane = t & 63, wid = t >> 6;
    if (lane == 0) wsum[wid] = val;
    __syncthreads();
    if (t == 0) {
        float sm = wsum[0] + wsum[1] + wsum[2] + wsum[3];
        atomicAdd(out, sm * 5.9604644775390625e-08f);  // 1/(N*D) = 2^-24
    }
}

extern "C" void kernel_launch(void* const* d_in, const int* in_sizes, int n_in,
                              void* d_out, int out_size, void* d_ws, size_t ws_size,
                              hipStream_t stream) {
    const float4* m1 = (const float4*)d_in[0];
    const float4* m2 = (const float4*)d_in[1];
    const float* centers = (const float*)d_in[2];
    const int* targets = (const int*)d_in[3];
    float* out = (float*)d_out;

    gather_sum_kernel<<<NC * SPL, TPB, 0, stream>>>(m1, m2, targets, out);
    loss_kernel<<<512, 256, 0, stream>>>(centers, out);
}